// Round 15
// baseline (360.090 us; speedup 1.0000x reference)
//
#include <hip/hip_runtime.h>
#include <hip/hip_bf16.h>

#define DD 256
#define KC 1024
#define NT1 16    // pass-1: 16 tiles of 64 codes
#define NT2 32    // pass-2: 32 tiles of 32 codes

typedef __attribute__((ext_vector_type(4))) float f32x4;
typedef __attribute__((ext_vector_type(8))) short bf16x8;

#define MFMA16 __builtin_amdgcn_mfma_f32_16x16x32_bf16

// Raw barrier: LDS ordering only (T4). Global stores/prefetch stay in flight.
#define BAR() do { \
    asm volatile("s_waitcnt lgkmcnt(0)" ::: "memory"); \
    __builtin_amdgcn_s_barrier(); \
    __builtin_amdgcn_sched_barrier(0); \
} while (0)

static __device__ __forceinline__ short f2bf(float f) {
    union { float f; unsigned u; } v; v.f = f;
    unsigned u = v.u;
    unsigned r = u + 0x7fffu + ((u >> 16) & 1u);
    return (short)(r >> 16);
}
static __device__ __forceinline__ float bf2f(short s) {
    union { unsigned u; float f; } v;
    v.u = ((unsigned)(unsigned short)s) << 16;
    return v.f;
}
static __device__ __forceinline__ unsigned pk2(float a, float b) {
    return (unsigned)(unsigned short)f2bf(a) |
           ((unsigned)(unsigned short)f2bf(b) << 16);
}

// ---------------------------------------------------------------------------
// prep: W fp32 [1024][256] -> wbf bf16 [1024][256], wtbf bf16 [256][1024],
//       wsq[k] = sum_d W[k][d]^2 / 256
// ---------------------------------------------------------------------------
__global__ void prep_kernel(const float* __restrict__ w, short* __restrict__ wbf,
                            short* __restrict__ wtbf, float* __restrict__ wsq) {
    const int cod = blockIdx.x;
    const int d   = threadIdx.x;           // 256 threads
    float v = w[cod * DD + d];
    short b = f2bf(v);
    wbf[cod * DD + d] = b;
    wtbf[d * KC + cod] = b;
    float s = v * v;
    #pragma unroll
    for (int m = 32; m >= 1; m >>= 1) s += __shfl_xor(s, m, 64);
    __shared__ float ps[4];
    const int wave = threadIdx.x >> 6, lane = threadIdx.x & 63;
    if (lane == 0) ps[wave] = s;
    __syncthreads();
    if (threadIdx.x == 0) {
        wsq[cod] = (ps[0] + ps[1] + ps[2] + ps[3]) * (1.0f / (float)DD);
    }
}

// ---------------------------------------------------------------------------
// Fused kernel, 64 rows/block, 512 thr (8 waves = rg[2 row-halves] x cg[4
// code-strips]).
// PASS 1 (16 tiles x 64 codes): wt_ SINGLE-buffered (32 KB) so total LDS is
//   76 KB -> 2 blocks/CU (R14's 64 KB dbuf forced 1 block/CU and regressed).
//   2 raw barriers/tile; tile i+1 global loads stay in flight across both.
//   Each wave holds 32 x-rows (xa[2][8]) -> each W-fragment read feeds 2
//   MFMAs (pass-1 LDS reads half of R12's).
// PASS 2 (32 tiles x 32 codes): R12 PV core verbatim.
// __launch_bounds__(512,4): VGPR cap 128 — R14 proved this state fits.
// ---------------------------------------------------------------------------
__global__ __launch_bounds__(512, 4) void fused_kernel(
    const float* __restrict__ x, const short* __restrict__ wbf,
    const short* __restrict__ wtbf, const float* __restrict__ wsq,
    float* __restrict__ qdist, float* __restrict__ quant)
{
    __shared__ short wt_[64 * DD];        // 32 KB single buffer: [code][256 d]
    __shared__ short wtT_[2][128 * 64];   // 16 KB each: superrow layout, swizzled
    __shared__ short et_[2][64 * 36];     // 4.6 KB each: q bf16 [row][32+4pad]
    __shared__ float red_[4][64];
    __shared__ float invs_[64];

    const int t   = threadIdx.x;
    const int w   = t >> 6, l = t & 63;
    const int lhi = l >> 4, llo = l & 15;
    const int rg  = w >> 2, cg = w & 3;
    const long rowbase = (long)blockIdx.x * 64;

    // pass-1 staging identity: 64-code tile = 32 KB; 64B/thread
    const int sc1 = t >> 3;              // code 0..63
    const int gq  = (t & 7) * 4;         // granule base 0,4,...,28
    // pass-2 wtT staging identity
    const int sd  = t >> 1;              // d 0..255
    const int sg2 = (t & 1) * 2;
    const int ssr = sd >> 1;
    const int shb = (sd & 1) * 4;

    bf16x8 wpf[4];

    // ---- issue W tile0 loads ----
    {
        const short* p = wbf + (size_t)sc1 * DD + gq * 8;
        #pragma unroll
        for (int j = 0; j < 4; j++) wpf[j] = *(const bf16x8*)(p + j * 8);
    }

    // ---- x fragments: 32 rows/wave (rows rg*32 + g*16 + llo) ----
    bf16x8 xa[2][8];
    #pragma unroll
    for (int g = 0; g < 2; g++) {
        const float* xr = x + (rowbase + rg * 32 + g * 16 + llo) * DD + lhi * 8;
        #pragma unroll
        for (int kk = 0; kk < 8; kk++) {
            f32x4 v0 = *(const f32x4*)(xr + kk * 32);
            f32x4 v1 = *(const f32x4*)(xr + kk * 32 + 4);
            bf16x8 b;
            b[0]=f2bf(v0[0]); b[1]=f2bf(v0[1]); b[2]=f2bf(v0[2]); b[3]=f2bf(v0[3]);
            b[4]=f2bf(v1[0]); b[5]=f2bf(v1[1]); b[6]=f2bf(v1[2]); b[7]=f2bf(v1[3]);
            xa[g][kk] = b;
        }
    }

    const int mycode = cg * 16 + llo;      // code within 64-tile, 0..63
    const int cswz   = mycode & 7;
    float wscur  = wsq[mycode];
    float wsnext = wsq[64 + mycode];

    float rs[2][4] = {{0.f,0.f,0.f,0.f},{0.f,0.f,0.f,0.f}};
    unsigned epk[NT1][2][2];               // [tile][rowgrp][pair] — VGPRs only

    // =================== PASS 1: scores (single-buffer wt_) ================
    #pragma unroll
    for (int i = 0; i < NT1; i++) {
        if (i) BAR();                      // all reads of tile i-1 done
        // write staged regs -> wt_
        {
            char* wb = (char*)wt_ + sc1 * 512;
            #pragma unroll
            for (int j = 0; j < 4; j++)
                *(bf16x8*)(wb + (((gq + j) ^ (sc1 & 7)) << 4)) = wpf[j];
        }
        if (i < NT1 - 1) {                 // issue tile i+1 loads (in flight)
            const short* p = wbf + (size_t)((i + 1) * 64 + sc1) * DD + gq * 8;
            #pragma unroll
            for (int j = 0; j < 4; j++) wpf[j] = *(const bf16x8*)(p + j * 8);
        }
        BAR();                             // wt_ visible
        char* wb2 = (char*)wt_ + mycode * 512;
        f32x4 s0 = {0.f,0.f,0.f,0.f}, s1 = {0.f,0.f,0.f,0.f};
        #pragma unroll
        for (int kk = 0; kk < 8; kk++) {
            bf16x8 bb = *(const bf16x8*)(wb2 + (((kk * 4 + lhi) ^ cswz) << 4));
            s0 = MFMA16(xa[0][kk], bb, s0, 0, 0, 0);
            s1 = MFMA16(xa[1][kk], bb, s1, 0, 0, 0);
        }
        {
            float e0 = __expf(s0[0] * (1.0f/128.0f) - wscur);
            float e1 = __expf(s0[1] * (1.0f/128.0f) - wscur);
            float e2 = __expf(s0[2] * (1.0f/128.0f) - wscur);
            float e3 = __expf(s0[3] * (1.0f/128.0f) - wscur);
            rs[0][0] += e0; rs[0][1] += e1; rs[0][2] += e2; rs[0][3] += e3;
            epk[i][0][0] = pk2(e0, e1); epk[i][0][1] = pk2(e2, e3);
        }
        {
            float e0 = __expf(s1[0] * (1.0f/128.0f) - wscur);
            float e1 = __expf(s1[1] * (1.0f/128.0f) - wscur);
            float e2 = __expf(s1[2] * (1.0f/128.0f) - wscur);
            float e3 = __expf(s1[3] * (1.0f/128.0f) - wscur);
            rs[1][0] += e0; rs[1][1] += e1; rs[1][2] += e2; rs[1][3] += e3;
            epk[i][1][0] = pk2(e0, e1); epk[i][1][1] = pk2(e2, e3);
        }
        wscur = wsnext;
        if (i < NT1 - 2) wsnext = wsq[(i + 2) * 64 + mycode];
    }

    // ---- issue wtT tile0 loads early (cover under reduction) ----
    bf16x8 tpf0, tpf1;
    { const short* p = wtbf + (size_t)sd * KC + sg2 * 8;
      tpf0 = *(const bf16x8*)p; tpf1 = *(const bf16x8*)(p + 8); }

    // ---- rowsum reduce -> invs ----
    #pragma unroll
    for (int m = 1; m <= 8; m <<= 1)
        #pragma unroll
        for (int g = 0; g < 2; g++)
            #pragma unroll
            for (int r = 0; r < 4; r++)
                rs[g][r] += __shfl_xor(rs[g][r], m, 64);
    if (llo == 0) {
        #pragma unroll
        for (int g = 0; g < 2; g++)
            #pragma unroll
            for (int r = 0; r < 4; r++)
                red_[cg][rg * 32 + g * 16 + lhi * 4 + r] = rs[g][r];
    }
    __syncthreads();
    if (t < 64) invs_[t] = 1.0f / (red_[0][t] + red_[1][t] + red_[2][t] + red_[3][t]);
    __syncthreads();

    float inv8[2][4];
    #pragma unroll
    for (int g = 0; g < 2; g++)
        #pragma unroll
        for (int r = 0; r < 4; r++)
            inv8[g][r] = invs_[rg * 32 + g * 16 + lhi * 4 + r];

    f32x4 uacc[4][2];   // transposed PV: D[d][row] (R9/R12-verified map)
    #pragma unroll
    for (int a = 0; a < 4; a++)
        #pragma unroll
        for (int b = 0; b < 2; b++) uacc[a][b] = (f32x4){0.f, 0.f, 0.f, 0.f};

    float* qbase = qdist + rowbase * KC;
    const int qrow = t >> 3, c4 = (t & 7) * 4;   // qdist store identity
    const int ci   = (cg & 1) * 16 + llo;        // code-in-32-tile for et writes
    const int chalf = cg >> 1;                   // which 32-half this wave holds

    // =================== PASS 2: PV + outputs (R12 core) ===================
    #pragma unroll
    for (int k = 0; k < NT2; k++) {
        const int b = k & 1;
        // et write: only waves whose cg-half owns codes [k*32, k*32+32)
        if (chalf == (k & 1)) {
            const int t16 = k >> 1;
            #pragma unroll
            for (int g = 0; g < 2; g++) {
                const unsigned p0 = epk[t16][g][0], p1 = epk[t16][g][1];
                const int row0 = rg * 32 + g * 16 + lhi * 4;
                et_[b][(row0 + 0) * 36 + ci] = f2bf(bf2f((short)(p0 & 0xffff)) * inv8[g][0]);
                et_[b][(row0 + 1) * 36 + ci] = f2bf(bf2f((short)(p0 >> 16))    * inv8[g][1]);
                et_[b][(row0 + 2) * 36 + ci] = f2bf(bf2f((short)(p1 & 0xffff)) * inv8[g][2]);
                et_[b][(row0 + 3) * 36 + ci] = f2bf(bf2f((short)(p1 >> 16))    * inv8[g][3]);
            }
        }
        // stage wtT tile k -> wtT_[b]
        {
            char* tb = (char*)wtT_[b] + ssr * 128;
            *(bf16x8*)(tb + (((shb + sg2    ) ^ (ssr & 7)) << 4)) = tpf0;
            *(bf16x8*)(tb + (((shb + sg2 + 1) ^ (ssr & 7)) << 4)) = tpf1;
        }
        if (k < NT2 - 1) {                 // load wtT tile k+1
            const short* p = wtbf + (size_t)sd * KC + (k + 1) * 32 + sg2 * 8;
            tpf0 = *(const bf16x8*)p; tpf1 = *(const bf16x8*)(p + 8);
        }
        BAR();
        // qdist store, full-line vectorized: 4 bf16 from et_ -> one f32x4
        {
            const char* ep = (const char*)et_[b] + qrow * 72 + c4 * 2;
            unsigned u0 = *(const unsigned*)ep;
            unsigned u1 = *(const unsigned*)(ep + 4);
            f32x4 o;
            o[0] = bf2f((short)(u0 & 0xffff)); o[1] = bf2f((short)(u0 >> 16));
            o[2] = bf2f((short)(u1 & 0xffff)); o[3] = bf2f((short)(u1 >> 16));
            *(f32x4*)(qbase + (size_t)qrow * KC + (size_t)k * 32 + c4) = o;
        }
        // PV from et_[b] + wtT_[b]
        bf16x8 bb0, bb1;
        {
            const int d0 = w * 32 + llo;
            bb0 = *(const bf16x8*)((char*)wtT_[b] + (d0 >> 1) * 128 +
                    (((((d0 & 1) << 2) + lhi) ^ ((d0 >> 1) & 7)) << 4));
            const int d1 = w * 32 + 16 + llo;
            bb1 = *(const bf16x8*)((char*)wtT_[b] + (d1 >> 1) * 128 +
                    (((((d1 & 1) << 2) + lhi) ^ ((d1 >> 1) & 7)) << 4));
        }
        #pragma unroll
        for (int rowg = 0; rowg < 4; rowg++) {
            bf16x8 aa = *(const bf16x8*)((char*)et_[b] + (rowg * 16 + llo) * 72 + lhi * 16);
            uacc[rowg][0] = MFMA16(bb0, aa, uacc[rowg][0], 0, 0, 0);
            uacc[rowg][1] = MFMA16(bb1, aa, uacc[rowg][1], 0, 0, 0);
        }
    }

    // quant stores: uacc[rowg][dg] = D[d][row] -> f32x4 along d
    #pragma unroll
    for (int rowg = 0; rowg < 4; rowg++)
        #pragma unroll
        for (int dg = 0; dg < 2; dg++)
            *(f32x4*)(quant + (rowbase + rowg * 16 + llo) * DD + w * 32 + dg * 16 + lhi * 4)
                = uacc[rowg][dg];
}

// ---------------------------------------------------------------------------
extern "C" void kernel_launch(void* const* d_in, const int* in_sizes, int n_in,
                              void* d_out, int out_size, void* d_ws, size_t ws_size,
                              hipStream_t stream) {
    const float* x = (const float*)d_in[0];
    const float* w = (const float*)d_in[1];
    float* out = (float*)d_out;

    const int nrows = in_sizes[0] / DD;          // 65536
    float* quant = out;                          // [nrows][256]
    float* qdist = out + (size_t)nrows * DD;     // [nrows][1024]

    short* wbf  = (short*)d_ws;                  // 1024*256 bf16 = 512 KB
    short* wtbf = wbf + (size_t)KC * DD;         // 256*1024 bf16 = 512 KB
    float* wsq  = (float*)(wtbf + (size_t)DD * KC);  // 1024 fp32

    prep_kernel<<<KC, DD, 0, stream>>>(w, wbf, wtbf, wsq);
    fused_kernel<<<nrows / 64, 512, 0, stream>>>(x, wbf, wtbf, wsq, qdist, quant);
}

// Round 16
// 189.533 us; speedup vs baseline: 1.8999x; 1.8999x over previous
//
#include <hip/hip_runtime.h>
#include <hip/hip_bf16.h>

#define DD 256
#define KC 1024
#define NT1 16    // pass-1: 16 tiles of 64 codes
#define NT2 32    // pass-2: 32 tiles of 32 codes

typedef __attribute__((ext_vector_type(4))) float f32x4;
typedef __attribute__((ext_vector_type(8))) short bf16x8;

#define MFMA16 __builtin_amdgcn_mfma_f32_16x16x32_bf16

// Raw barrier: LDS ordering only (T4). Global stores/prefetch stay in flight.
#define BAR() do { \
    asm volatile("s_waitcnt lgkmcnt(0)" ::: "memory"); \
    __builtin_amdgcn_s_barrier(); \
    __builtin_amdgcn_sched_barrier(0); \
} while (0)

static __device__ __forceinline__ short f2bf(float f) {
    union { float f; unsigned u; } v; v.f = f;
    unsigned u = v.u;
    unsigned r = u + 0x7fffu + ((u >> 16) & 1u);
    return (short)(r >> 16);
}
static __device__ __forceinline__ float bf2f(short s) {
    union { unsigned u; float f; } v;
    v.u = ((unsigned)(unsigned short)s) << 16;
    return v.f;
}
static __device__ __forceinline__ unsigned pk2(float a, float b) {
    return (unsigned)(unsigned short)f2bf(a) |
           ((unsigned)(unsigned short)f2bf(b) << 16);
}

// ---------------------------------------------------------------------------
// prep: W fp32 [1024][256] -> wbf bf16 [1024][256], wtbf bf16 [256][1024],
//       wsq[k] = sum_d W[k][d]^2 / 256
// ---------------------------------------------------------------------------
__global__ void prep_kernel(const float* __restrict__ w, short* __restrict__ wbf,
                            short* __restrict__ wtbf, float* __restrict__ wsq) {
    const int cod = blockIdx.x;
    const int d   = threadIdx.x;           // 256 threads
    float v = w[cod * DD + d];
    short b = f2bf(v);
    wbf[cod * DD + d] = b;
    wtbf[d * KC + cod] = b;
    float s = v * v;
    #pragma unroll
    for (int m = 32; m >= 1; m >>= 1) s += __shfl_xor(s, m, 64);
    __shared__ float ps[4];
    const int wave = threadIdx.x >> 6, lane = threadIdx.x & 63;
    if (lane == 0) ps[wave] = s;
    __syncthreads();
    if (threadIdx.x == 0) {
        wsq[cod] = (ps[0] + ps[1] + ps[2] + ps[3]) * (1.0f / (float)DD);
    }
}

// ---------------------------------------------------------------------------
// Fused kernel, 64 rows/block, 512 thr (8 waves = rg[2 row-halves] x cg[4
// code-strips]).
// PASS 1 (16 tiles x 64 codes): wt_ SINGLE-buffered (32 KB), total LDS 76 KB
//   -> 2 blocks/CU at VGPR<=128. 2 raw barriers/tile; tile i+1 global loads
//   stay in flight across both. 32 x-rows/wave: each W-fragment read feeds
//   2 MFMAs (pass-1 LDS reads = half of R12).
// PASS 2 (32 tiles x 32 codes): R12 PV core verbatim.
// LAUNCH BOUNDS: (512,2). NEVER (512,4): the allocator then drops to the
//   64-VGPR tier and spills epk wholesale (R10/R11/R15, 3x confirmed:
//   +300 MB fetch / +450 MB write of scratch traffic). Under (512,2) the
//   allocator chooses exactly 128 VGPR for this state (R14) -> 2 blocks/CU.
// ---------------------------------------------------------------------------
__global__ __launch_bounds__(512, 2) void fused_kernel(
    const float* __restrict__ x, const short* __restrict__ wbf,
    const short* __restrict__ wtbf, const float* __restrict__ wsq,
    float* __restrict__ qdist, float* __restrict__ quant)
{
    __shared__ short wt_[64 * DD];        // 32 KB single buffer: [code][256 d]
    __shared__ short wtT_[2][128 * 64];   // 16 KB each: superrow layout, swizzled
    __shared__ short et_[2][64 * 36];     // 4.6 KB each: q bf16 [row][32+4pad]
    __shared__ float red_[4][64];
    __shared__ float invs_[64];

    const int t   = threadIdx.x;
    const int w   = t >> 6, l = t & 63;
    const int lhi = l >> 4, llo = l & 15;
    const int rg  = w >> 2, cg = w & 3;
    const long rowbase = (long)blockIdx.x * 64;

    // pass-1 staging identity: 64-code tile = 32 KB; 64B/thread
    const int sc1 = t >> 3;              // code 0..63
    const int gq  = (t & 7) * 4;         // granule base 0,4,...,28
    // pass-2 wtT staging identity
    const int sd  = t >> 1;              // d 0..255
    const int sg2 = (t & 1) * 2;
    const int ssr = sd >> 1;
    const int shb = (sd & 1) * 4;

    bf16x8 wpf[4];

    // ---- issue W tile0 loads ----
    {
        const short* p = wbf + (size_t)sc1 * DD + gq * 8;
        #pragma unroll
        for (int j = 0; j < 4; j++) wpf[j] = *(const bf16x8*)(p + j * 8);
    }

    // ---- x fragments: 32 rows/wave (rows rg*32 + g*16 + llo) ----
    bf16x8 xa[2][8];
    #pragma unroll
    for (int g = 0; g < 2; g++) {
        const float* xr = x + (rowbase + rg * 32 + g * 16 + llo) * DD + lhi * 8;
        #pragma unroll
        for (int kk = 0; kk < 8; kk++) {
            f32x4 v0 = *(const f32x4*)(xr + kk * 32);
            f32x4 v1 = *(const f32x4*)(xr + kk * 32 + 4);
            bf16x8 b;
            b[0]=f2bf(v0[0]); b[1]=f2bf(v0[1]); b[2]=f2bf(v0[2]); b[3]=f2bf(v0[3]);
            b[4]=f2bf(v1[0]); b[5]=f2bf(v1[1]); b[6]=f2bf(v1[2]); b[7]=f2bf(v1[3]);
            xa[g][kk] = b;
        }
    }

    const int mycode = cg * 16 + llo;      // code within 64-tile, 0..63
    const int cswz   = mycode & 7;
    float wscur  = wsq[mycode];
    float wsnext = wsq[64 + mycode];

    float rs[2][4] = {{0.f,0.f,0.f,0.f},{0.f,0.f,0.f,0.f}};
    unsigned epk[NT1][2][2];               // [tile][rowgrp][pair] — VGPRs only

    // =================== PASS 1: scores (single-buffer wt_) ================
    #pragma unroll
    for (int i = 0; i < NT1; i++) {
        if (i) BAR();                      // all reads of tile i-1 done
        // write staged regs -> wt_
        {
            char* wb = (char*)wt_ + sc1 * 512;
            #pragma unroll
            for (int j = 0; j < 4; j++)
                *(bf16x8*)(wb + (((gq + j) ^ (sc1 & 7)) << 4)) = wpf[j];
        }
        if (i < NT1 - 1) {                 // issue tile i+1 loads (in flight)
            const short* p = wbf + (size_t)((i + 1) * 64 + sc1) * DD + gq * 8;
            #pragma unroll
            for (int j = 0; j < 4; j++) wpf[j] = *(const bf16x8*)(p + j * 8);
        }
        BAR();                             // wt_ visible
        char* wb2 = (char*)wt_ + mycode * 512;
        f32x4 s0 = {0.f,0.f,0.f,0.f}, s1 = {0.f,0.f,0.f,0.f};
        #pragma unroll
        for (int kk = 0; kk < 8; kk++) {
            bf16x8 bb = *(const bf16x8*)(wb2 + (((kk * 4 + lhi) ^ cswz) << 4));
            s0 = MFMA16(xa[0][kk], bb, s0, 0, 0, 0);
            s1 = MFMA16(xa[1][kk], bb, s1, 0, 0, 0);
        }
        {
            float e0 = __expf(s0[0] * (1.0f/128.0f) - wscur);
            float e1 = __expf(s0[1] * (1.0f/128.0f) - wscur);
            float e2 = __expf(s0[2] * (1.0f/128.0f) - wscur);
            float e3 = __expf(s0[3] * (1.0f/128.0f) - wscur);
            rs[0][0] += e0; rs[0][1] += e1; rs[0][2] += e2; rs[0][3] += e3;
            epk[i][0][0] = pk2(e0, e1); epk[i][0][1] = pk2(e2, e3);
        }
        {
            float e0 = __expf(s1[0] * (1.0f/128.0f) - wscur);
            float e1 = __expf(s1[1] * (1.0f/128.0f) - wscur);
            float e2 = __expf(s1[2] * (1.0f/128.0f) - wscur);
            float e3 = __expf(s1[3] * (1.0f/128.0f) - wscur);
            rs[1][0] += e0; rs[1][1] += e1; rs[1][2] += e2; rs[1][3] += e3;
            epk[i][1][0] = pk2(e0, e1); epk[i][1][1] = pk2(e2, e3);
        }
        wscur = wsnext;
        if (i < NT1 - 2) wsnext = wsq[(i + 2) * 64 + mycode];
    }

    // ---- issue wtT tile0 loads early (cover under reduction) ----
    bf16x8 tpf0, tpf1;
    { const short* p = wtbf + (size_t)sd * KC + sg2 * 8;
      tpf0 = *(const bf16x8*)p; tpf1 = *(const bf16x8*)(p + 8); }

    // ---- rowsum reduce -> invs ----
    #pragma unroll
    for (int m = 1; m <= 8; m <<= 1)
        #pragma unroll
        for (int g = 0; g < 2; g++)
            #pragma unroll
            for (int r = 0; r < 4; r++)
                rs[g][r] += __shfl_xor(rs[g][r], m, 64);
    if (llo == 0) {
        #pragma unroll
        for (int g = 0; g < 2; g++)
            #pragma unroll
            for (int r = 0; r < 4; r++)
                red_[cg][rg * 32 + g * 16 + lhi * 4 + r] = rs[g][r];
    }
    __syncthreads();
    if (t < 64) invs_[t] = 1.0f / (red_[0][t] + red_[1][t] + red_[2][t] + red_[3][t]);
    __syncthreads();

    float inv8[2][4];
    #pragma unroll
    for (int g = 0; g < 2; g++)
        #pragma unroll
        for (int r = 0; r < 4; r++)
            inv8[g][r] = invs_[rg * 32 + g * 16 + lhi * 4 + r];

    f32x4 uacc[4][2];   // transposed PV: D[d][row] (R9/R12-verified map)
    #pragma unroll
    for (int a = 0; a < 4; a++)
        #pragma unroll
        for (int b = 0; b < 2; b++) uacc[a][b] = (f32x4){0.f, 0.f, 0.f, 0.f};

    float* qbase = qdist + rowbase * KC;
    const int qrow = t >> 3, c4 = (t & 7) * 4;   // qdist store identity
    const int ci   = (cg & 1) * 16 + llo;        // code-in-32-tile for et writes
    const int chalf = cg >> 1;                   // which 32-half this wave holds

    // =================== PASS 2: PV + outputs (R12 core) ===================
    #pragma unroll
    for (int k = 0; k < NT2; k++) {
        const int b = k & 1;
        // et write: only waves whose cg-half owns codes [k*32, k*32+32)
        if (chalf == (k & 1)) {
            const int t16 = k >> 1;
            #pragma unroll
            for (int g = 0; g < 2; g++) {
                const unsigned p0 = epk[t16][g][0], p1 = epk[t16][g][1];
                const int row0 = rg * 32 + g * 16 + lhi * 4;
                et_[b][(row0 + 0) * 36 + ci] = f2bf(bf2f((short)(p0 & 0xffff)) * inv8[g][0]);
                et_[b][(row0 + 1) * 36 + ci] = f2bf(bf2f((short)(p0 >> 16))    * inv8[g][1]);
                et_[b][(row0 + 2) * 36 + ci] = f2bf(bf2f((short)(p1 & 0xffff)) * inv8[g][2]);
                et_[b][(row0 + 3) * 36 + ci] = f2bf(bf2f((short)(p1 >> 16))    * inv8[g][3]);
            }
        }
        // stage wtT tile k -> wtT_[b]
        {
            char* tb = (char*)wtT_[b] + ssr * 128;
            *(bf16x8*)(tb + (((shb + sg2    ) ^ (ssr & 7)) << 4)) = tpf0;
            *(bf16x8*)(tb + (((shb + sg2 + 1) ^ (ssr & 7)) << 4)) = tpf1;
        }
        if (k < NT2 - 1) {                 // load wtT tile k+1
            const short* p = wtbf + (size_t)sd * KC + (k + 1) * 32 + sg2 * 8;
            tpf0 = *(const bf16x8*)p; tpf1 = *(const bf16x8*)(p + 8);
        }
        BAR();
        // qdist store, full-line vectorized: 4 bf16 from et_ -> one f32x4
        {
            const char* ep = (const char*)et_[b] + qrow * 72 + c4 * 2;
            unsigned u0 = *(const unsigned*)ep;
            unsigned u1 = *(const unsigned*)(ep + 4);
            f32x4 o;
            o[0] = bf2f((short)(u0 & 0xffff)); o[1] = bf2f((short)(u0 >> 16));
            o[2] = bf2f((short)(u1 & 0xffff)); o[3] = bf2f((short)(u1 >> 16));
            *(f32x4*)(qbase + (size_t)qrow * KC + (size_t)k * 32 + c4) = o;
        }
        // PV from et_[b] + wtT_[b]
        bf16x8 bb0, bb1;
        {
            const int d0 = w * 32 + llo;
            bb0 = *(const bf16x8*)((char*)wtT_[b] + (d0 >> 1) * 128 +
                    (((((d0 & 1) << 2) + lhi) ^ ((d0 >> 1) & 7)) << 4));
            const int d1 = w * 32 + 16 + llo;
            bb1 = *(const bf16x8*)((char*)wtT_[b] + (d1 >> 1) * 128 +
                    (((((d1 & 1) << 2) + lhi) ^ ((d1 >> 1) & 7)) << 4));
        }
        #pragma unroll
        for (int rowg = 0; rowg < 4; rowg++) {
            bf16x8 aa = *(const bf16x8*)((char*)et_[b] + (rowg * 16 + llo) * 72 + lhi * 16);
            uacc[rowg][0] = MFMA16(bb0, aa, uacc[rowg][0], 0, 0, 0);
            uacc[rowg][1] = MFMA16(bb1, aa, uacc[rowg][1], 0, 0, 0);
        }
    }

    // quant stores: uacc[rowg][dg] = D[d][row] -> f32x4 along d
    #pragma unroll
    for (int rowg = 0; rowg < 4; rowg++)
        #pragma unroll
        for (int dg = 0; dg < 2; dg++)
            *(f32x4*)(quant + (rowbase + rowg * 16 + llo) * DD + w * 32 + dg * 16 + lhi * 4)
                = uacc[rowg][dg];
}

// ---------------------------------------------------------------------------
extern "C" void kernel_launch(void* const* d_in, const int* in_sizes, int n_in,
                              void* d_out, int out_size, void* d_ws, size_t ws_size,
                              hipStream_t stream) {
    const float* x = (const float*)d_in[0];
    const float* w = (const float*)d_in[1];
    float* out = (float*)d_out;

    const int nrows = in_sizes[0] / DD;          // 65536
    float* quant = out;                          // [nrows][256]
    float* qdist = out + (size_t)nrows * DD;     // [nrows][1024]

    short* wbf  = (short*)d_ws;                  // 1024*256 bf16 = 512 KB
    short* wtbf = wbf + (size_t)KC * DD;         // 256*1024 bf16 = 512 KB
    float* wsq  = (float*)(wtbf + (size_t)DD * KC);  // 1024 fp32

    prep_kernel<<<KC, DD, 0, stream>>>(w, wbf, wtbf, wsq);
    fused_kernel<<<nrows / 64, 512, 0, stream>>>(x, wbf, wtbf, wsq, qdist, quant);
}